// Round 10
// baseline (301.316 us; speedup 1.0000x reference)
//
#include <hip/hip_runtime.h>

typedef unsigned short u16;
typedef __attribute__((ext_vector_type(8))) short bf16x8;
typedef __attribute__((ext_vector_type(4))) float f32x4;

__device__ __forceinline__ float bf2f(u16 h) {
    return __uint_as_float(((unsigned int)h) << 16);
}
__device__ __forceinline__ u16 f2bf(float f) {
    unsigned int u = __float_as_uint(f);
    u += 0x7FFFu + ((u >> 16) & 1u);   // RNE
    return (u16)(u >> 16);
}

// async global->LDS, 16 B per lane. LDS dest = wave-uniform base + lane*16.
__device__ __forceinline__ void gl2lds16(const u16* g, u16* l) {
    __builtin_amdgcn_global_load_lds(
        (const __attribute__((address_space(1))) unsigned int*)g,
        (__attribute__((address_space(3))) unsigned int*)l,
        16, 0, 0);
}

// ---------------------------------------------------------------------------
// Dtype detection (fp32 vs bf16 input buffers). flag=1 -> bf16.
// ---------------------------------------------------------------------------
__global__ void detect_dtype(const u16* __restrict__ x, int* __restrict__ flag) {
    __shared__ int cnt;
    if (threadIdx.x == 0) cnt = 0;
    __syncthreads();
    unsigned e = (x[2 * threadIdx.x] >> 7) & 0xFF;
    if (e >= 116 && e <= 132) atomicAdd(&cnt, 1);
    __syncthreads();
    if (threadIdx.x == 0) *flag = (cnt >= 96) ? 1 : 0;
}

// ---------------------------------------------------------------------------
// Elementwise convert to bf16 (or bit-copy). n4 = n/4.
// ---------------------------------------------------------------------------
__global__ __launch_bounds__(256) void convert_in(
    const void* __restrict__ in, u16* __restrict__ out, long n4,
    const int* __restrict__ flag)
{
    long i = (long)blockIdx.x * blockDim.x + threadIdx.x;
    if (i >= n4) return;
    if (*flag) {
        ((ushort4*)out)[i] = ((const ushort4*)in)[i];
    } else {
        float4 v = ((const float4*)in)[i];
        ushort4 r;
        r.x = f2bf(v.x); r.y = f2bf(v.y); r.z = f2bf(v.z); r.w = f2bf(v.w);
        ((ushort4*)out)[i] = r;
    }
}

// ---------------------------------------------------------------------------
// Transpose [R x Cc] -> [Cc x R] with dtype convert fused (weights).
// ---------------------------------------------------------------------------
__global__ __launch_bounds__(256) void transpose_conv(
    const void* __restrict__ in, u16* __restrict__ out, int R, int Cc,
    const int* __restrict__ flag)
{
    __shared__ u16 tile[32][33];
    int tx = threadIdx.x & 31, ty = threadIdx.x >> 5;
    int c0 = blockIdx.x * 32, r0 = blockIdx.y * 32;
    bool isbf = (*flag != 0);
#pragma unroll
    for (int g = 0; g < 4; ++g) {
        size_t idx = (size_t)(r0 + ty + g * 8) * Cc + c0 + tx;
        tile[ty + g * 8][tx] = isbf ? ((const u16*)in)[idx]
                                    : f2bf(((const float*)in)[idx]);
    }
    __syncthreads();
#pragma unroll
    for (int g = 0; g < 4; ++g)
        out[(size_t)(c0 + ty + g * 8) * R + r0 + tx] = tile[tx][ty + g * 8];
}

// ---------------------------------------------------------------------------
// Fused QKV GEMM. A[M,1024] bf16, Bt[3072,1024] = [Wq^T;Wk^T;Wv^T] bf16.
// Q written PRE-SCALED by 1/sqrt(d)*log2(e) (attn works in exp2 domain);
// K written [M,1024]; V written transposed: Vt[(b*16+h)*64+d][T].
// ---------------------------------------------------------------------------
__global__ __launch_bounds__(256, 2) void gemm_qkv(
    const u16* __restrict__ A, const u16* __restrict__ Bt,
    const void* __restrict__ biasq, const void* __restrict__ biask,
    const void* __restrict__ biasv,
    u16* __restrict__ Qo, u16* __restrict__ Ko, u16* __restrict__ Vt,
    int M, int K, const int* __restrict__ flag)
{
    __shared__ __align__(16) u16 As[128 * 64];
    __shared__ __align__(16) u16 Bs[128 * 64];

    const int tid  = threadIdx.x;
    const int m0   = blockIdx.y * 128, n0 = blockIdx.x * 128;
    const int lane = tid & 63, wid = tid >> 6;
    const int wm   = (wid >> 1) * 64, wn = (wid & 1) * 64;
    const int m16  = lane & 15, quad = lane >> 4;
    const int isbf = *flag;

    const int srow   = wid * 8 + (lane >> 3);
    const int schunk = (lane & 7) * 8;

    f32x4 acc[4][4];
#pragma unroll
    for (int i = 0; i < 4; ++i)
#pragma unroll
        for (int j = 0; j < 4; ++j)
            acc[i][j] = (f32x4){0.f, 0.f, 0.f, 0.f};

    for (int k0 = 0; k0 < K; k0 += 64) {
#pragma unroll
        for (int g = 0; g < 4; ++g) {
            int r = g * 32 + srow;
            gl2lds16(&A[(size_t)(m0 + r) * K + k0 + schunk], &As[r * 64 + schunk]);
            gl2lds16(&Bt[(size_t)(n0 + r) * K + k0 + schunk], &Bs[r * 64 + schunk]);
        }
        __syncthreads();
#pragma unroll
        for (int ks = 0; ks < 64; ks += 32) {
            bf16x8 a[4], b[4];
#pragma unroll
            for (int i = 0; i < 4; ++i)
                a[i] = *(bf16x8*)&As[(wm + i * 16 + m16) * 64 + ks + quad * 8];
#pragma unroll
            for (int j = 0; j < 4; ++j)
                b[j] = *(bf16x8*)&Bs[(wn + j * 16 + m16) * 64 + ks + quad * 8];
#pragma unroll
            for (int i = 0; i < 4; ++i)
#pragma unroll
                for (int j = 0; j < 4; ++j)
                    acc[i][j] = __builtin_amdgcn_mfma_f32_16x16x32_bf16(
                        a[i], b[j], acc[i][j], 0, 0, 0);
        }
        __syncthreads();
    }

    const int region = n0 >> 10;                 // 0=Q 1=K 2=V
    const void* bias = (region == 0) ? biasq : (region == 1) ? biask : biasv;
    const int nbase = region << 10;
    const float osc = (region == 0) ? (0.125f * 1.44269504f) : 1.0f;

#pragma unroll
    for (int i = 0; i < 4; ++i) {
        int grow = m0 + wm + i * 16 + quad * 4;
#pragma unroll
        for (int j = 0; j < 4; ++j) {
            int gcol = n0 + wn + j * 16 + m16;
            int nl = gcol - nbase;               // 0..1023 within region
            float bv_ = isbf ? bf2f(((const u16*)bias)[nl])
                             : ((const float*)bias)[nl];
            if (region < 2) {
                u16* out = (region == 0) ? Qo : Ko;
#pragma unroll
                for (int r = 0; r < 4; ++r)
                    out[(size_t)(grow + r) * 1024 + nl] =
                        f2bf((acc[i][j][r] + bv_) * osc);
            } else {
                int h = nl >> 6, dd = nl & 63;
                int bb = grow >> 11, s = grow & 2047;
                ushort4 pk;
                pk.x = f2bf(acc[i][j][0] + bv_);
                pk.y = f2bf(acc[i][j][1] + bv_);
                pk.z = f2bf(acc[i][j][2] + bv_);
                pk.w = f2bf(acc[i][j][3] + bv_);
                *(ushort4*)&Vt[(((size_t)bb * 16 + h) * 64 + dd) * 2048 + s] = pk;
            }
        }
    }
}

// ---------------------------------------------------------------------------
// C[M,N] = A[M,K] @ W + bias (final projection). Bt = W^T [N,K] bf16.
// ---------------------------------------------------------------------------
__global__ __launch_bounds__(256, 2) void gemm_bias(
    const u16* __restrict__ A, const u16* __restrict__ Bt,
    const void* __restrict__ bias, void* __restrict__ C,
    int M, int N, int K, int final_out, const int* __restrict__ flag)
{
    __shared__ __align__(16) u16 As[128 * 64];
    __shared__ __align__(16) u16 Bs[128 * 64];

    const int tid  = threadIdx.x;
    const int m0   = blockIdx.y * 128, n0 = blockIdx.x * 128;
    const int lane = tid & 63, wid = tid >> 6;
    const int wm   = (wid >> 1) * 64, wn = (wid & 1) * 64;
    const int m16  = lane & 15, quad = lane >> 4;
    const int isbf = *flag;

    const int srow   = wid * 8 + (lane >> 3);
    const int schunk = (lane & 7) * 8;

    f32x4 acc[4][4];
#pragma unroll
    for (int i = 0; i < 4; ++i)
#pragma unroll
        for (int j = 0; j < 4; ++j)
            acc[i][j] = (f32x4){0.f, 0.f, 0.f, 0.f};

    for (int k0 = 0; k0 < K; k0 += 64) {
#pragma unroll
        for (int g = 0; g < 4; ++g) {
            int r = g * 32 + srow;
            gl2lds16(&A[(size_t)(m0 + r) * K + k0 + schunk], &As[r * 64 + schunk]);
            gl2lds16(&Bt[(size_t)(n0 + r) * K + k0 + schunk], &Bs[r * 64 + schunk]);
        }
        __syncthreads();
#pragma unroll
        for (int ks = 0; ks < 64; ks += 32) {
            bf16x8 a[4], b[4];
#pragma unroll
            for (int i = 0; i < 4; ++i)
                a[i] = *(bf16x8*)&As[(wm + i * 16 + m16) * 64 + ks + quad * 8];
#pragma unroll
            for (int j = 0; j < 4; ++j)
                b[j] = *(bf16x8*)&Bs[(wn + j * 16 + m16) * 64 + ks + quad * 8];
#pragma unroll
            for (int i = 0; i < 4; ++i)
#pragma unroll
                for (int j = 0; j < 4; ++j)
                    acc[i][j] = __builtin_amdgcn_mfma_f32_16x16x32_bf16(
                        a[i], b[j], acc[i][j], 0, 0, 0);
        }
        __syncthreads();
    }

    const bool out_f32 = final_out && !isbf;
#pragma unroll
    for (int i = 0; i < 4; ++i) {
        int grow = m0 + wm + i * 16 + quad * 4;
#pragma unroll
        for (int j = 0; j < 4; ++j) {
            int gcol = n0 + wn + j * 16 + m16;
            float bv = isbf ? bf2f(((const u16*)bias)[gcol])
                            : ((const float*)bias)[gcol];
#pragma unroll
            for (int r = 0; r < 4; ++r) {
                float val = acc[i][j][r] + bv;
                size_t idx = (size_t)(grow + r) * N + gcol;
                if (out_f32) ((float*)C)[idx] = val;
                else         ((u16*)C)[idx]   = f2bf(val);
            }
        }
    }
}

// ---------------------------------------------------------------------------
// Flash attention (causal), S^T orientation, exp2-domain (Q pre-scaled),
// NO online max (scores Cauchy-Schwarz bounded). 64x64 tiles, 2-wave
// blocks, double-buffered K/V DMA, ONE barrier per tile-iter.
// LOAD-BALANCED: block bx does q-tile (31-bx) then bx = 33 iters each.
// Grid = 1024 blocks; LDS 40 KB -> 4 blocks/CU (4 barrier domains/CU).
// Ks/Vts/Ps XOR-swizzled at 16B; Ps same-wave private (no barrier).
// ---------------------------------------------------------------------------
__global__ __launch_bounds__(128, 2) void attn_flash(
    const u16* __restrict__ Q, const u16* __restrict__ Kb,
    const u16* __restrict__ Vt, u16* __restrict__ O, int T, int C)
{
    __shared__ __align__(16) u16 Ks[2][64 * 64];    // [s][d], swizzled
    __shared__ __align__(16) u16 Vts[2][64 * 64];   // [d][s], swizzled
    __shared__ __align__(16) u16 Ps[64 * 64];       // [q][s], swizzled

    const int tid  = threadIdx.x;
    const int lane = tid & 63, wid = tid >> 6;      // wid 0..1
    const int m16  = lane & 15, quad = lane >> 4;
    const int sw   = m16 & 7;                       // XOR swizzle key
    const int h = blockIdx.y, b = blockIdx.z;
    const float NEG = -3.0e4f;                      // exp2(NEG) == 0

    const size_t headoff = ((size_t)b * T) * C + h * 64;
    const size_t vthead  = ((size_t)(b * 16 + h) * 64) * T;
    const int ntiles = 2 * gridDim.x;               // 32 q-tiles of 64 rows

    const int srow8 = tid >> 3;                     // 0..15
    const int sch   = tid & 7;

    for (int phase = 0; phase < 2; ++phase) {
        const int qt = phase ? (int)blockIdx.x : (ntiles - 1) - (int)blockIdx.x;
        if (phase) __syncthreads();   // protect LDS from phase-0 reads

        // Q B-fragments (pre-scaled in gemm_qkv): rows qt*64+wid*32+i*16+m16
        bf16x8 aq[2][2];
#pragma unroll
        for (int i = 0; i < 2; ++i)
#pragma unroll
            for (int ks = 0; ks < 2; ++ks)
                aq[i][ks] = *(const bf16x8*)&Q[headoff +
                    (size_t)(qt * 64 + wid * 32 + i * 16 + m16) * C +
                    ks * 32 + quad * 8];

        // prologue: DMA s-tile 0 into buffer 0
#pragma unroll
        for (int g = 0; g < 4; ++g) {
            int r  = g * 16 + srow8;
            int cg = sch ^ (r & 7);
            gl2lds16(&Kb[headoff + (size_t)r * C + cg * 8],
                     &Ks[0][r * 64 + sch * 8]);
        }
#pragma unroll
        for (int g = 0; g < 4; ++g) {
            int r  = g * 16 + srow8;
            int cg = sch ^ (r & 7);
            gl2lds16(&Vt[vthead + (size_t)r * T + cg * 8],
                     &Vts[0][r * 64 + sch * 8]);
        }

        float l_run[2] = {0.f, 0.f};
        f32x4 o_acc[2][4];
#pragma unroll
        for (int i = 0; i < 2; ++i)
#pragma unroll
            for (int n = 0; n < 4; ++n)
                o_acc[i][n] = (f32x4){0.f, 0.f, 0.f, 0.f};

        const int nst = qt + 1;
        for (int st = 0; st < nst; ++st) {
            __syncthreads();   // tile st resident; prev-tile reads done
            const int cur = st & 1;

            // prefetch tile st+1 (drains at NEXT barrier)
            if (st + 1 < nst) {
                const int nxt = cur ^ 1;
#pragma unroll
                for (int g = 0; g < 4; ++g) {
                    int r  = g * 16 + srow8;
                    int cg = sch ^ (r & 7);
                    gl2lds16(&Kb[headoff + (size_t)((st + 1) * 64 + r) * C + cg * 8],
                             &Ks[nxt][r * 64 + sch * 8]);
                }
#pragma unroll
                for (int g = 0; g < 4; ++g) {
                    int r  = g * 16 + srow8;
                    int cg = sch ^ (r & 7);
                    gl2lds16(&Vt[vthead + (size_t)r * T + (st + 1) * 64 + cg * 8],
                             &Vts[nxt][r * 64 + sch * 8]);
                }
            }

            // S^T = K Q^T : lane's q = i*16+m16 (col), s = j*16+quad*4+r (row)
            f32x4 sacc[2][4];
#pragma unroll
            for (int i = 0; i < 2; ++i)
#pragma unroll
                for (int j = 0; j < 4; ++j)
                    sacc[i][j] = (f32x4){0.f, 0.f, 0.f, 0.f};
#pragma unroll
            for (int ks = 0; ks < 2; ++ks) {
                bf16x8 bk[4];
#pragma unroll
                for (int j = 0; j < 4; ++j)
                    bk[j] = *(bf16x8*)&Ks[cur][(j * 16 + m16) * 64 +
                                              (((ks * 4 + quad) ^ sw) * 8)];
#pragma unroll
                for (int i = 0; i < 2; ++i)
#pragma unroll
                    for (int j = 0; j < 4; ++j)
                        sacc[i][j] = __builtin_amdgcn_mfma_f32_16x16x32_bf16(
                            bk[j], aq[i][ks], sacc[i][j], 0, 0, 0);
            }

            // diagonal tile: causal mask (wave-uniform branch)
            if (st == qt) {
#pragma unroll
                for (int i = 0; i < 2; ++i) {
                    const int q_in = wid * 32 + i * 16 + m16;
#pragma unroll
                    for (int j = 0; j < 4; ++j)
#pragma unroll
                        for (int r = 0; r < 4; ++r)
                            if ((j * 16 + quad * 4 + r) > q_in)
                                sacc[i][j][r] = NEG;
                }
            }

            // exp2 (Q pre-scaled: no mul, no max) + packed bf16 Ps write
            float rs[2] = {0.f, 0.f};
#pragma unroll
            for (int i = 0; i < 2; ++i) {
#pragma unroll
                for (int j = 0; j < 4; ++j) {
                    float p0 = exp2f(sacc[i][j][0]);
                    float p1 = exp2f(sacc[i][j][1]);
                    float p2 = exp2f(sacc[i][j][2]);
                    float p3 = exp2f(sacc[i][j][3]);
                    rs[i] += (p0 + p1) + (p2 + p3);
                    unsigned lo = ((__float_as_uint(p0) + 0x8000u) >> 16) |
                                  ((__float_as_uint(p1) + 0x8000u) & 0xFFFF0000u);
                    unsigned hi = ((__float_as_uint(p2) + 0x8000u) >> 16) |
                                  ((__float_as_uint(p3) + 0x8000u) & 0xFFFF0000u);
                    *(uint2*)&Ps[(wid * 32 + i * 16 + m16) * 64 +
                                 (((j * 2 + (quad >> 1)) ^ sw) * 8) +
                                 (quad & 1) * 4] = make_uint2(lo, hi);
                }
            }

            // PV (Ps same-wave private: lgkmcnt ordering only)
#pragma unroll
            for (int k4 = 0; k4 < 2; ++k4) {
                bf16x8 ap[2], bv[4];
#pragma unroll
                for (int i = 0; i < 2; ++i)
                    ap[i] = *(bf16x8*)&Ps[(wid * 32 + i * 16 + m16) * 64 +
                                          (((k4 * 4 + quad) ^ sw) * 8)];
#pragma unroll
                for (int n = 0; n < 4; ++n)
                    bv[n] = *(bf16x8*)&Vts[cur][(n * 16 + m16) * 64 +
                                               (((k4 * 4 + quad) ^ sw) * 8)];
#pragma unroll
                for (int i = 0; i < 2; ++i)
#pragma unroll
                    for (int n = 0; n < 4; ++n)
                        o_acc[i][n] = __builtin_amdgcn_mfma_f32_16x16x32_bf16(
                            ap[i], bv[n], o_acc[i][n], 0, 0, 0);
            }
            l_run[0] += rs[0];
            l_run[1] += rs[1];
        }

        // epilogue: quad-reduce l, normalize, store
#pragma unroll
        for (int i = 0; i < 2; ++i) {
            l_run[i] += __shfl_xor(l_run[i], 16);
            l_run[i] += __shfl_xor(l_run[i], 32);
            float linv[4];
#pragma unroll
            for (int r = 0; r < 4; ++r)
                linv[r] = 1.f / __shfl(l_run[i], quad * 4 + r);
#pragma unroll
            for (int n = 0; n < 4; ++n) {
#pragma unroll
                for (int r = 0; r < 4; ++r) {
                    int tq = qt * 64 + wid * 32 + i * 16 + quad * 4 + r;
                    O[((size_t)b * T + tq) * C + h * 64 + n * 16 + m16] =
                        f2bf(o_acc[i][n][r] * linv[r]);
                }
            }
        }
    }
}

// ---------------------------------------------------------------------------
extern "C" void kernel_launch(void* const* d_in, const int* in_sizes, int n_in,
                              void* d_out, int out_size, void* d_ws, size_t ws_size,
                              hipStream_t stream)
{
    const void* x  = d_in[0];
    const void* Wq = d_in[1];
    const void* bq = d_in[2];
    const void* Wk = d_in[3];
    const void* bk = d_in[4];
    const void* Wv = d_in[5];
    const void* bv = d_in[6];
    const void* Wp = d_in[7];
    const void* bp = d_in[8];

    const int Bb = 4, T = 2048, C = 1024, H = 16;
    const int M = Bb * T, N = C, K = C;

    u16* wsp = (u16*)d_ws;
    const size_t WSZ = (size_t)C * C;
    const size_t MSZ = (size_t)M * C;
    u16* WtQKV = wsp;                 // [3072][1024]
    u16* WtP   = wsp + 3 * WSZ;
    u16* xb    = wsp + 4 * WSZ;
    u16* Qb    = xb + MSZ;            // Q pre-scaled by 1/8*log2(e)
    u16* Kbf   = Qb + MSZ;
    u16* Vtb   = Kbf + MSZ;           // V^T: [(b*16+h)*64+d][T]
    u16* tmp   = Vtb + MSZ;           // attention out
    int* flag  = (int*)(tmp + MSZ);

    detect_dtype<<<1, 128, 0, stream>>>((const u16*)x, flag);
    convert_in<<<(int)(MSZ / 4 / 256), 256, 0, stream>>>(x, xb, MSZ / 4, flag);

    dim3 tb(256), tg(C / 32, C / 32);
    transpose_conv<<<tg, tb, 0, stream>>>(Wq, WtQKV,           C, C, flag);
    transpose_conv<<<tg, tb, 0, stream>>>(Wk, WtQKV + WSZ,     C, C, flag);
    transpose_conv<<<tg, tb, 0, stream>>>(Wv, WtQKV + 2 * WSZ, C, C, flag);
    transpose_conv<<<tg, tb, 0, stream>>>(Wp, WtP,             C, C, flag);

    dim3 qg(3 * N / 128, M / 128), qb(256);
    gemm_qkv<<<qg, qb, 0, stream>>>(xb, WtQKV, bq, bk, bv, Qb, Kbf, Vtb,
                                    M, K, flag);

    dim3 ag(T / 128, H, Bb), ab(128);   // 1024 blocks x 2 waves, 2 q64-tiles each
    attn_flash<<<ag, ab, 0, stream>>>(Qb, Kbf, Vtb, tmp, T, C);

    dim3 gg(N / 128, M / 128), gb(256);
    gemm_bias<<<gg, gb, 0, stream>>>(tmp, WtP, bp, d_out, M, N, K, 1, flag);
}

// Round 11
// 285.905 us; speedup vs baseline: 1.0539x; 1.0539x over previous
//
#include <hip/hip_runtime.h>

typedef unsigned short u16;
typedef __attribute__((ext_vector_type(8))) short bf16x8;
typedef __attribute__((ext_vector_type(4))) float f32x4;

__device__ __forceinline__ float bf2f(u16 h) {
    return __uint_as_float(((unsigned int)h) << 16);
}
__device__ __forceinline__ u16 f2bf(float f) {
    unsigned int u = __float_as_uint(f);
    u += 0x7FFFu + ((u >> 16) & 1u);   // RNE
    return (u16)(u >> 16);
}

// async global->LDS, 16 B per lane. LDS dest = wave-uniform base + lane*16.
__device__ __forceinline__ void gl2lds16(const u16* g, u16* l) {
    __builtin_amdgcn_global_load_lds(
        (const __attribute__((address_space(1))) unsigned int*)g,
        (__attribute__((address_space(3))) unsigned int*)l,
        16, 0, 0);
}

// ---------------------------------------------------------------------------
// Dtype detection (fp32 vs bf16 input buffers). flag=1 -> bf16.
// ---------------------------------------------------------------------------
__global__ void detect_dtype(const u16* __restrict__ x, int* __restrict__ flag) {
    __shared__ int cnt;
    if (threadIdx.x == 0) cnt = 0;
    __syncthreads();
    unsigned e = (x[2 * threadIdx.x] >> 7) & 0xFF;
    if (e >= 116 && e <= 132) atomicAdd(&cnt, 1);
    __syncthreads();
    if (threadIdx.x == 0) *flag = (cnt >= 96) ? 1 : 0;
}

// ---------------------------------------------------------------------------
// Elementwise convert to bf16 (or bit-copy). n4 = n/4.
// ---------------------------------------------------------------------------
__global__ __launch_bounds__(256) void convert_in(
    const void* __restrict__ in, u16* __restrict__ out, long n4,
    const int* __restrict__ flag)
{
    long i = (long)blockIdx.x * blockDim.x + threadIdx.x;
    if (i >= n4) return;
    if (*flag) {
        ((ushort4*)out)[i] = ((const ushort4*)in)[i];
    } else {
        float4 v = ((const float4*)in)[i];
        ushort4 r;
        r.x = f2bf(v.x); r.y = f2bf(v.y); r.z = f2bf(v.z); r.w = f2bf(v.w);
        ((ushort4*)out)[i] = r;
    }
}

// ---------------------------------------------------------------------------
// Transpose [R x Cc] -> [Cc x R] with dtype convert fused (weights).
// ---------------------------------------------------------------------------
__global__ __launch_bounds__(256) void transpose_conv(
    const void* __restrict__ in, u16* __restrict__ out, int R, int Cc,
    const int* __restrict__ flag)
{
    __shared__ u16 tile[32][33];
    int tx = threadIdx.x & 31, ty = threadIdx.x >> 5;
    int c0 = blockIdx.x * 32, r0 = blockIdx.y * 32;
    bool isbf = (*flag != 0);
#pragma unroll
    for (int g = 0; g < 4; ++g) {
        size_t idx = (size_t)(r0 + ty + g * 8) * Cc + c0 + tx;
        tile[ty + g * 8][tx] = isbf ? ((const u16*)in)[idx]
                                    : f2bf(((const float*)in)[idx]);
    }
    __syncthreads();
#pragma unroll
    for (int g = 0; g < 4; ++g)
        out[(size_t)(c0 + ty + g * 8) * R + r0 + tx] = tile[tx][ty + g * 8];
}

// ---------------------------------------------------------------------------
// Fused QKV GEMM. A[M,1024] bf16, Bt[3072,1024] = [Wq^T;Wk^T;Wv^T] bf16.
// Q written PRE-SCALED by 1/sqrt(d)*log2(e) (attn works in exp2 domain);
// K written [M,1024]; V written transposed: Vt[(b*16+h)*64+d][T].
// ---------------------------------------------------------------------------
__global__ __launch_bounds__(256, 2) void gemm_qkv(
    const u16* __restrict__ A, const u16* __restrict__ Bt,
    const void* __restrict__ biasq, const void* __restrict__ biask,
    const void* __restrict__ biasv,
    u16* __restrict__ Qo, u16* __restrict__ Ko, u16* __restrict__ Vt,
    int M, int K, const int* __restrict__ flag)
{
    __shared__ __align__(16) u16 As[128 * 64];
    __shared__ __align__(16) u16 Bs[128 * 64];

    const int tid  = threadIdx.x;
    const int m0   = blockIdx.y * 128, n0 = blockIdx.x * 128;
    const int lane = tid & 63, wid = tid >> 6;
    const int wm   = (wid >> 1) * 64, wn = (wid & 1) * 64;
    const int m16  = lane & 15, quad = lane >> 4;
    const int isbf = *flag;

    const int srow   = wid * 8 + (lane >> 3);
    const int schunk = (lane & 7) * 8;

    f32x4 acc[4][4];
#pragma unroll
    for (int i = 0; i < 4; ++i)
#pragma unroll
        for (int j = 0; j < 4; ++j)
            acc[i][j] = (f32x4){0.f, 0.f, 0.f, 0.f};

    for (int k0 = 0; k0 < K; k0 += 64) {
#pragma unroll
        for (int g = 0; g < 4; ++g) {
            int r = g * 32 + srow;
            gl2lds16(&A[(size_t)(m0 + r) * K + k0 + schunk], &As[r * 64 + schunk]);
            gl2lds16(&Bt[(size_t)(n0 + r) * K + k0 + schunk], &Bs[r * 64 + schunk]);
        }
        __syncthreads();
#pragma unroll
        for (int ks = 0; ks < 64; ks += 32) {
            bf16x8 a[4], b[4];
#pragma unroll
            for (int i = 0; i < 4; ++i)
                a[i] = *(bf16x8*)&As[(wm + i * 16 + m16) * 64 + ks + quad * 8];
#pragma unroll
            for (int j = 0; j < 4; ++j)
                b[j] = *(bf16x8*)&Bs[(wn + j * 16 + m16) * 64 + ks + quad * 8];
#pragma unroll
            for (int i = 0; i < 4; ++i)
#pragma unroll
                for (int j = 0; j < 4; ++j)
                    acc[i][j] = __builtin_amdgcn_mfma_f32_16x16x32_bf16(
                        a[i], b[j], acc[i][j], 0, 0, 0);
        }
        __syncthreads();
    }

    const int region = n0 >> 10;                 // 0=Q 1=K 2=V
    const void* bias = (region == 0) ? biasq : (region == 1) ? biask : biasv;
    const int nbase = region << 10;
    const float osc = (region == 0) ? (0.125f * 1.44269504f) : 1.0f;

#pragma unroll
    for (int i = 0; i < 4; ++i) {
        int grow = m0 + wm + i * 16 + quad * 4;
#pragma unroll
        for (int j = 0; j < 4; ++j) {
            int gcol = n0 + wn + j * 16 + m16;
            int nl = gcol - nbase;               // 0..1023 within region
            float bv_ = isbf ? bf2f(((const u16*)bias)[nl])
                             : ((const float*)bias)[nl];
            if (region < 2) {
                u16* out = (region == 0) ? Qo : Ko;
#pragma unroll
                for (int r = 0; r < 4; ++r)
                    out[(size_t)(grow + r) * 1024 + nl] =
                        f2bf((acc[i][j][r] + bv_) * osc);
            } else {
                int h = nl >> 6, dd = nl & 63;
                int bb = grow >> 11, s = grow & 2047;
                ushort4 pk;
                pk.x = f2bf(acc[i][j][0] + bv_);
                pk.y = f2bf(acc[i][j][1] + bv_);
                pk.z = f2bf(acc[i][j][2] + bv_);
                pk.w = f2bf(acc[i][j][3] + bv_);
                *(ushort4*)&Vt[(((size_t)bb * 16 + h) * 64 + dd) * 2048 + s] = pk;
            }
        }
    }
}

// ---------------------------------------------------------------------------
// C[M,N] = A[M,K] @ W + bias (final projection). Bt = W^T [N,K] bf16.
// ---------------------------------------------------------------------------
__global__ __launch_bounds__(256, 2) void gemm_bias(
    const u16* __restrict__ A, const u16* __restrict__ Bt,
    const void* __restrict__ bias, void* __restrict__ C,
    int M, int N, int K, int final_out, const int* __restrict__ flag)
{
    __shared__ __align__(16) u16 As[128 * 64];
    __shared__ __align__(16) u16 Bs[128 * 64];

    const int tid  = threadIdx.x;
    const int m0   = blockIdx.y * 128, n0 = blockIdx.x * 128;
    const int lane = tid & 63, wid = tid >> 6;
    const int wm   = (wid >> 1) * 64, wn = (wid & 1) * 64;
    const int m16  = lane & 15, quad = lane >> 4;
    const int isbf = *flag;

    const int srow   = wid * 8 + (lane >> 3);
    const int schunk = (lane & 7) * 8;

    f32x4 acc[4][4];
#pragma unroll
    for (int i = 0; i < 4; ++i)
#pragma unroll
        for (int j = 0; j < 4; ++j)
            acc[i][j] = (f32x4){0.f, 0.f, 0.f, 0.f};

    for (int k0 = 0; k0 < K; k0 += 64) {
#pragma unroll
        for (int g = 0; g < 4; ++g) {
            int r = g * 32 + srow;
            gl2lds16(&A[(size_t)(m0 + r) * K + k0 + schunk], &As[r * 64 + schunk]);
            gl2lds16(&Bt[(size_t)(n0 + r) * K + k0 + schunk], &Bs[r * 64 + schunk]);
        }
        __syncthreads();
#pragma unroll
        for (int ks = 0; ks < 64; ks += 32) {
            bf16x8 a[4], b[4];
#pragma unroll
            for (int i = 0; i < 4; ++i)
                a[i] = *(bf16x8*)&As[(wm + i * 16 + m16) * 64 + ks + quad * 8];
#pragma unroll
            for (int j = 0; j < 4; ++j)
                b[j] = *(bf16x8*)&Bs[(wn + j * 16 + m16) * 64 + ks + quad * 8];
#pragma unroll
            for (int i = 0; i < 4; ++i)
#pragma unroll
                for (int j = 0; j < 4; ++j)
                    acc[i][j] = __builtin_amdgcn_mfma_f32_16x16x32_bf16(
                        a[i], b[j], acc[i][j], 0, 0, 0);
        }
        __syncthreads();
    }

    const bool out_f32 = final_out && !isbf;
#pragma unroll
    for (int i = 0; i < 4; ++i) {
        int grow = m0 + wm + i * 16 + quad * 4;
#pragma unroll
        for (int j = 0; j < 4; ++j) {
            int gcol = n0 + wn + j * 16 + m16;
            float bv = isbf ? bf2f(((const u16*)bias)[gcol])
                            : ((const float*)bias)[gcol];
#pragma unroll
            for (int r = 0; r < 4; ++r) {
                float val = acc[i][j][r] + bv;
                size_t idx = (size_t)(grow + r) * N + gcol;
                if (out_f32) ((float*)C)[idx] = val;
                else         ((u16*)C)[idx]   = f2bf(val);
            }
        }
    }
}

// ---------------------------------------------------------------------------
// Flash attention (causal), S^T orientation, exp2-domain (Q pre-scaled),
// NO online max. 128x128 tiles, 4-wave blocks, double-buffered K/V DMA,
// ONE barrier per tile-iter, Ps 128x64 half-buffer (2 s-halves).
// LOAD-BALANCED: each block runs q-tile (15-bx) then bx = 17 iters.
// XCD-PINNED: flat block id remapped so bh == lin (mod 8) -> all 8 blocks
// of one (b,h) land on one XCD (round-robin dispatch assumption); per-XCD
// K/V working set = 8 bh x 512 KB = 4 MB = L2.
// LDS 80 KB -> 2 blocks/CU. Ks/Vts/Ps XOR-swizzled; Ps same-wave private.
// ---------------------------------------------------------------------------
__global__ __launch_bounds__(256, 2) void attn_flash(
    const u16* __restrict__ Q, const u16* __restrict__ Kb,
    const u16* __restrict__ Vt, u16* __restrict__ O, int T, int C)
{
    __shared__ __align__(16) u16 Ks[2][128 * 64];    // [s][d], swizzled
    __shared__ __align__(16) u16 Vts[2][64 * 128];   // [d][s], swizzled
    __shared__ __align__(16) u16 Ps[128 * 64];       // [q][s_half], swizzled

    const int tid  = threadIdx.x;
    const int lane = tid & 63, wid = tid >> 6;
    const int m16  = lane & 15, quad = lane >> 4;
    const int sw   = m16 & 7;                      // XOR swizzle key
    const float NEG = -3.0e4f;                     // exp2(NEG) == 0

    // XCD-pinning remap: lin = bx + 8*(y + 16*z), 0..511
    const int lin = (int)(blockIdx.x +
                          gridDim.x * (blockIdx.y + gridDim.y * blockIdx.z));
    const int bh  = (lin & 7) + 8 * ((lin >> 3) & 7);   // 0..63, == lin mod 8
    const int bx  = lin >> 6;                           // 0..7
    const int b = bh >> 4, h = bh & 15;

    const size_t headoff = ((size_t)b * T) * C + h * 64;
    const size_t vthead  = ((size_t)bh * 64) * T;
    const int ntiles = 16;                              // q-tiles of 128 rows

    for (int phase = 0; phase < 2; ++phase) {
        const int qt = phase ? bx : (ntiles - 1) - bx;
        if (phase) __syncthreads();   // protect LDS from phase-0 reads

        // Q B-fragments (pre-scaled by 1/8*log2e in gemm_qkv)
        bf16x8 aq[2][2];
#pragma unroll
        for (int i = 0; i < 2; ++i)
#pragma unroll
            for (int ks = 0; ks < 2; ++ks)
                aq[i][ks] = *(const bf16x8*)&Q[headoff +
                    (size_t)(qt * 128 + wid * 32 + i * 16 + m16) * C +
                    ks * 32 + quad * 8];

        // prologue: DMA tile 0 into buffer 0
#pragma unroll
        for (int g = 0; g < 4; ++g) {
            int r  = g * 32 + wid * 8 + (lane >> 3);
            int cg = (lane & 7) ^ (r & 7);
            gl2lds16(&Kb[headoff + (size_t)r * C + cg * 8],
                     &Ks[0][r * 64 + (lane & 7) * 8]);
        }
#pragma unroll
        for (int g = 0; g < 4; ++g) {
            int r  = g * 16 + wid * 4 + (lane >> 4);
            int cg = (lane & 15) ^ (r & 7);
            gl2lds16(&Vt[vthead + (size_t)r * T + cg * 8],
                     &Vts[0][r * 128 + (lane & 15) * 8]);
        }

        float l_run[2] = {0.f, 0.f};
        f32x4 o_acc[2][4];
#pragma unroll
        for (int i = 0; i < 2; ++i)
#pragma unroll
            for (int n = 0; n < 4; ++n)
                o_acc[i][n] = (f32x4){0.f, 0.f, 0.f, 0.f};

        for (int st = 0; st <= qt; ++st) {
            __syncthreads();   // tile st resident; prev-tile reads done
            const int cur = st & 1;

            // prefetch tile st+1 (drains at NEXT barrier)
            if (st < qt) {
                const int nxt = cur ^ 1;
#pragma unroll
                for (int g = 0; g < 4; ++g) {
                    int r  = g * 32 + wid * 8 + (lane >> 3);
                    int cg = (lane & 7) ^ (r & 7);
                    gl2lds16(&Kb[headoff + (size_t)((st + 1) * 128 + r) * C + cg * 8],
                             &Ks[nxt][r * 64 + (lane & 7) * 8]);
                }
#pragma unroll
                for (int g = 0; g < 4; ++g) {
                    int r  = g * 16 + wid * 4 + (lane >> 4);
                    int cg = (lane & 15) ^ (r & 7);
                    gl2lds16(&Vt[vthead + (size_t)r * T + (st + 1) * 128 + cg * 8],
                             &Vts[nxt][r * 128 + (lane & 15) * 8]);
                }
            }

            // S^T = K Q^T : lane's q = i*16+m16 (col), s = j*16+quad*4+r (row)
            f32x4 sacc[2][8];
#pragma unroll
            for (int i = 0; i < 2; ++i)
#pragma unroll
                for (int j = 0; j < 8; ++j)
                    sacc[i][j] = (f32x4){0.f, 0.f, 0.f, 0.f};
#pragma unroll
            for (int ks = 0; ks < 2; ++ks) {
                bf16x8 bk[8];
#pragma unroll
                for (int j = 0; j < 8; ++j)
                    bk[j] = *(bf16x8*)&Ks[cur][(j * 16 + m16) * 64 +
                                              (((ks * 4 + quad) ^ sw) * 8)];
#pragma unroll
                for (int i = 0; i < 2; ++i)
#pragma unroll
                    for (int j = 0; j < 8; ++j)
                        sacc[i][j] = __builtin_amdgcn_mfma_f32_16x16x32_bf16(
                            bk[j], aq[i][ks], sacc[i][j], 0, 0, 0);
            }

            // diagonal tile: causal mask (wave-uniform branch)
            if (st == qt) {
#pragma unroll
                for (int i = 0; i < 2; ++i) {
                    const int q_in = wid * 32 + i * 16 + m16;
#pragma unroll
                    for (int j = 0; j < 8; ++j)
#pragma unroll
                        for (int r = 0; r < 4; ++r)
                            if ((j * 16 + quad * 4 + r) > q_in)
                                sacc[i][j][r] = NEG;
                }
            }

            // exp2 (pre-scaled: no mul, no max) + Ps write + PV per s-half
            float rs[2] = {0.f, 0.f};
#pragma unroll
            for (int half = 0; half < 2; ++half) {
#pragma unroll
                for (int i = 0; i < 2; ++i) {
#pragma unroll
                    for (int jh = 0; jh < 4; ++jh) {
                        int j = half * 4 + jh;
                        float p0 = exp2f(sacc[i][j][0]);
                        float p1 = exp2f(sacc[i][j][1]);
                        float p2 = exp2f(sacc[i][j][2]);
                        float p3 = exp2f(sacc[i][j][3]);
                        rs[i] += (p0 + p1) + (p2 + p3);
                        unsigned lo = ((__float_as_uint(p0) + 0x8000u) >> 16) |
                                      ((__float_as_uint(p1) + 0x8000u) & 0xFFFF0000u);
                        unsigned hi = ((__float_as_uint(p2) + 0x8000u) >> 16) |
                                      ((__float_as_uint(p3) + 0x8000u) & 0xFFFF0000u);
                        *(uint2*)&Ps[(wid * 32 + i * 16 + m16) * 64 +
                                     (((jh * 2 + (quad >> 1)) ^ sw) * 8) +
                                     (quad & 1) * 4] = make_uint2(lo, hi);
                    }
                }
                // PV for this half (Ps same-wave private: no barrier)
#pragma unroll
                for (int k4l = 0; k4l < 2; ++k4l) {
                    int k4 = half * 2 + k4l;
                    bf16x8 ap[2], bv[4];
#pragma unroll
                    for (int i = 0; i < 2; ++i)
                        ap[i] = *(bf16x8*)&Ps[(wid * 32 + i * 16 + m16) * 64 +
                                              (((k4l * 4 + quad) ^ sw) * 8)];
#pragma unroll
                    for (int n = 0; n < 4; ++n)
                        bv[n] = *(bf16x8*)&Vts[cur][(n * 16 + m16) * 128 +
                                                   (((k4 * 4 + quad) ^ sw) * 8)];
#pragma unroll
                    for (int i = 0; i < 2; ++i)
#pragma unroll
                        for (int n = 0; n < 4; ++n)
                            o_acc[i][n] = __builtin_amdgcn_mfma_f32_16x16x32_bf16(
                                ap[i], bv[n], o_acc[i][n], 0, 0, 0);
                }
            }
            l_run[0] += rs[0];
            l_run[1] += rs[1];
        }

        // epilogue: quad-reduce l, normalize, store
#pragma unroll
        for (int i = 0; i < 2; ++i) {
            l_run[i] += __shfl_xor(l_run[i], 16);
            l_run[i] += __shfl_xor(l_run[i], 32);
            float linv[4];
#pragma unroll
            for (int r = 0; r < 4; ++r)
                linv[r] = 1.f / __shfl(l_run[i], quad * 4 + r);
#pragma unroll
            for (int n = 0; n < 4; ++n) {
#pragma unroll
                for (int r = 0; r < 4; ++r) {
                    int tq = qt * 128 + wid * 32 + i * 16 + quad * 4 + r;
                    O[((size_t)b * T + tq) * C + h * 64 + n * 16 + m16] =
                        f2bf(o_acc[i][n][r] * linv[r]);
                }
            }
        }
    }
}

// ---------------------------------------------------------------------------
extern "C" void kernel_launch(void* const* d_in, const int* in_sizes, int n_in,
                              void* d_out, int out_size, void* d_ws, size_t ws_size,
                              hipStream_t stream)
{
    const void* x  = d_in[0];
    const void* Wq = d_in[1];
    const void* bq = d_in[2];
    const void* Wk = d_in[3];
    const void* bk = d_in[4];
    const void* Wv = d_in[5];
    const void* bv = d_in[6];
    const void* Wp = d_in[7];
    const void* bp = d_in[8];

    const int Bb = 4, T = 2048, C = 1024, H = 16;
    const int M = Bb * T, N = C, K = C;

    u16* wsp = (u16*)d_ws;
    const size_t WSZ = (size_t)C * C;
    const size_t MSZ = (size_t)M * C;
    u16* WtQKV = wsp;                 // [3072][1024]
    u16* WtP   = wsp + 3 * WSZ;
    u16* xb    = wsp + 4 * WSZ;
    u16* Qb    = xb + MSZ;            // Q pre-scaled by 1/8*log2(e)
    u16* Kbf   = Qb + MSZ;
    u16* Vtb   = Kbf + MSZ;           // V^T: [(b*16+h)*64+d][T]
    u16* tmp   = Vtb + MSZ;           // attention out
    int* flag  = (int*)(tmp + MSZ);

    detect_dtype<<<1, 128, 0, stream>>>((const u16*)x, flag);
    convert_in<<<(int)(MSZ / 4 / 256), 256, 0, stream>>>(x, xb, MSZ / 4, flag);

    dim3 tb(256), tg(C / 32, C / 32);
    transpose_conv<<<tg, tb, 0, stream>>>(Wq, WtQKV,           C, C, flag);
    transpose_conv<<<tg, tb, 0, stream>>>(Wk, WtQKV + WSZ,     C, C, flag);
    transpose_conv<<<tg, tb, 0, stream>>>(Wv, WtQKV + 2 * WSZ, C, C, flag);
    transpose_conv<<<tg, tb, 0, stream>>>(Wp, WtP,             C, C, flag);

    dim3 qg(3 * N / 128, M / 128), qb(256);
    gemm_qkv<<<qg, qb, 0, stream>>>(xb, WtQKV, bq, bk, bv, Qb, Kbf, Vtb,
                                    M, K, flag);

    dim3 ag(T / 256, H, Bb), ab(256);   // 512 blocks, XCD-pinned remap inside
    attn_flash<<<ag, ab, 0, stream>>>(Qb, Kbf, Vtb, tmp, T, C);

    dim3 gg(N / 128, M / 128), gb(256);
    gemm_bias<<<gg, gb, 0, stream>>>(tmp, WtP, bp, d_out, M, N, K, 1, flag);
}

// Round 12
// 280.879 us; speedup vs baseline: 1.0728x; 1.0179x over previous
//
#include <hip/hip_runtime.h>

typedef unsigned short u16;
typedef __attribute__((ext_vector_type(8))) short bf16x8;
typedef __attribute__((ext_vector_type(4))) float f32x4;

__device__ __forceinline__ float bf2f(u16 h) {
    return __uint_as_float(((unsigned int)h) << 16);
}
__device__ __forceinline__ u16 f2bf(float f) {
    unsigned int u = __float_as_uint(f);
    u += 0x7FFFu + ((u >> 16) & 1u);   // RNE
    return (u16)(u >> 16);
}

// async global->LDS, 16 B per lane. LDS dest = wave-uniform base + lane*16.
__device__ __forceinline__ void gl2lds16(const u16* g, u16* l) {
    __builtin_amdgcn_global_load_lds(
        (const __attribute__((address_space(1))) unsigned int*)g,
        (__attribute__((address_space(3))) unsigned int*)l,
        16, 0, 0);
}

// ---------------------------------------------------------------------------
// Dtype detection (fp32 vs bf16 input buffers). flag=1 -> bf16.
// ---------------------------------------------------------------------------
__global__ void detect_dtype(const u16* __restrict__ x, int* __restrict__ flag) {
    __shared__ int cnt;
    if (threadIdx.x == 0) cnt = 0;
    __syncthreads();
    unsigned e = (x[2 * threadIdx.x] >> 7) & 0xFF;
    if (e >= 116 && e <= 132) atomicAdd(&cnt, 1);
    __syncthreads();
    if (threadIdx.x == 0) *flag = (cnt >= 96) ? 1 : 0;
}

// ---------------------------------------------------------------------------
// Elementwise convert to bf16 (or bit-copy). n4 = n/4.
// ---------------------------------------------------------------------------
__global__ __launch_bounds__(256) void convert_in(
    const void* __restrict__ in, u16* __restrict__ out, long n4,
    const int* __restrict__ flag)
{
    long i = (long)blockIdx.x * blockDim.x + threadIdx.x;
    if (i >= n4) return;
    if (*flag) {
        ((ushort4*)out)[i] = ((const ushort4*)in)[i];
    } else {
        float4 v = ((const float4*)in)[i];
        ushort4 r;
        r.x = f2bf(v.x); r.y = f2bf(v.y); r.z = f2bf(v.z); r.w = f2bf(v.w);
        ((ushort4*)out)[i] = r;
    }
}

// ---------------------------------------------------------------------------
// Transpose all 4 weights [C x C] -> [C x C]^T in ONE dispatch (z = which).
// z 0..2 -> WtQKV + z*C*C ; z=3 -> WtP. Dtype convert fused.
// ---------------------------------------------------------------------------
__global__ __launch_bounds__(256) void transpose_all(
    const void* __restrict__ W0, const void* __restrict__ W1,
    const void* __restrict__ W2, const void* __restrict__ W3,
    u16* __restrict__ outQKV, u16* __restrict__ outP,
    int Cc, const int* __restrict__ flag)
{
    __shared__ u16 tile[32][33];
    int tx = threadIdx.x & 31, ty = threadIdx.x >> 5;
    int c0 = blockIdx.x * 32, r0 = blockIdx.y * 32;
    int z = blockIdx.z;
    const void* in = (z == 0) ? W0 : (z == 1) ? W1 : (z == 2) ? W2 : W3;
    u16* out = (z < 3) ? (outQKV + (size_t)z * Cc * Cc) : outP;
    bool isbf = (*flag != 0);
#pragma unroll
    for (int g = 0; g < 4; ++g) {
        size_t idx = (size_t)(r0 + ty + g * 8) * Cc + c0 + tx;
        tile[ty + g * 8][tx] = isbf ? ((const u16*)in)[idx]
                                    : f2bf(((const float*)in)[idx]);
    }
    __syncthreads();
#pragma unroll
    for (int g = 0; g < 4; ++g)
        out[(size_t)(c0 + ty + g * 8) * Cc + r0 + tx] = tile[tx][ty + g * 8];
}

// ---------------------------------------------------------------------------
// Fused QKV GEMM. A[M,1024] bf16, Bt[3072,1024] = [Wq^T;Wk^T;Wv^T] bf16.
// LDS XOR-swizzled at 16B granularity (conflict-free frag reads).
// Q written PRE-SCALED by 1/sqrt(d)*log2(e); K [M,1024]; V transposed.
// ---------------------------------------------------------------------------
__global__ __launch_bounds__(256, 2) void gemm_qkv(
    const u16* __restrict__ A, const u16* __restrict__ Bt,
    const void* __restrict__ biasq, const void* __restrict__ biask,
    const void* __restrict__ biasv,
    u16* __restrict__ Qo, u16* __restrict__ Ko, u16* __restrict__ Vt,
    int M, int K, const int* __restrict__ flag)
{
    __shared__ __align__(16) u16 As[128 * 64];
    __shared__ __align__(16) u16 Bs[128 * 64];

    const int tid  = threadIdx.x;
    const int m0   = blockIdx.y * 128, n0 = blockIdx.x * 128;
    const int lane = tid & 63, wid = tid >> 6;
    const int wm   = (wid >> 1) * 64, wn = (wid & 1) * 64;
    const int m16  = lane & 15, quad = lane >> 4;
    const int sw   = m16 & 7;
    const int isbf = *flag;

    const int srow = wid * 8 + (lane >> 3);   // +g*32
    const int sch  = lane & 7;

    f32x4 acc[4][4];
#pragma unroll
    for (int i = 0; i < 4; ++i)
#pragma unroll
        for (int j = 0; j < 4; ++j)
            acc[i][j] = (f32x4){0.f, 0.f, 0.f, 0.f};

    for (int k0 = 0; k0 < K; k0 += 64) {
#pragma unroll
        for (int g = 0; g < 4; ++g) {
            int r  = g * 32 + srow;
            int cg = sch ^ (r & 7);
            gl2lds16(&A[(size_t)(m0 + r) * K + k0 + cg * 8], &As[r * 64 + sch * 8]);
            gl2lds16(&Bt[(size_t)(n0 + r) * K + k0 + cg * 8], &Bs[r * 64 + sch * 8]);
        }
        __syncthreads();
#pragma unroll
        for (int ks = 0; ks < 2; ++ks) {
            bf16x8 a[4], b[4];
#pragma unroll
            for (int i = 0; i < 4; ++i) {
                int row = wm + i * 16 + m16;
                a[i] = *(bf16x8*)&As[row * 64 + (((ks * 4 + quad) ^ sw) * 8)];
            }
#pragma unroll
            for (int j = 0; j < 4; ++j) {
                int row = wn + j * 16 + m16;
                b[j] = *(bf16x8*)&Bs[row * 64 + (((ks * 4 + quad) ^ sw) * 8)];
            }
#pragma unroll
            for (int i = 0; i < 4; ++i)
#pragma unroll
                for (int j = 0; j < 4; ++j)
                    acc[i][j] = __builtin_amdgcn_mfma_f32_16x16x32_bf16(
                        a[i], b[j], acc[i][j], 0, 0, 0);
        }
        __syncthreads();
    }

    const int region = n0 >> 10;                 // 0=Q 1=K 2=V
    const void* bias = (region == 0) ? biasq : (region == 1) ? biask : biasv;
    const int nbase = region << 10;
    const float osc = (region == 0) ? (0.125f * 1.44269504f) : 1.0f;

#pragma unroll
    for (int i = 0; i < 4; ++i) {
        int grow = m0 + wm + i * 16 + quad * 4;
#pragma unroll
        for (int j = 0; j < 4; ++j) {
            int gcol = n0 + wn + j * 16 + m16;
            int nl = gcol - nbase;               // 0..1023 within region
            float bv_ = isbf ? bf2f(((const u16*)bias)[nl])
                             : ((const float*)bias)[nl];
            if (region < 2) {
                u16* out = (region == 0) ? Qo : Ko;
#pragma unroll
                for (int r = 0; r < 4; ++r)
                    out[(size_t)(grow + r) * 1024 + nl] =
                        f2bf((acc[i][j][r] + bv_) * osc);
            } else {
                int h = nl >> 6, dd = nl & 63;
                int bb = grow >> 11, s = grow & 2047;
                ushort4 pk;
                pk.x = f2bf(acc[i][j][0] + bv_);
                pk.y = f2bf(acc[i][j][1] + bv_);
                pk.z = f2bf(acc[i][j][2] + bv_);
                pk.w = f2bf(acc[i][j][3] + bv_);
                *(ushort4*)&Vt[(((size_t)bb * 16 + h) * 64 + dd) * 2048 + s] = pk;
            }
        }
    }
}

// ---------------------------------------------------------------------------
// C[M,N] = A[M,K] @ W + bias (final projection). LDS XOR-swizzled.
// ---------------------------------------------------------------------------
__global__ __launch_bounds__(256, 2) void gemm_bias(
    const u16* __restrict__ A, const u16* __restrict__ Bt,
    const void* __restrict__ bias, void* __restrict__ C,
    int M, int N, int K, int final_out, const int* __restrict__ flag)
{
    __shared__ __align__(16) u16 As[128 * 64];
    __shared__ __align__(16) u16 Bs[128 * 64];

    const int tid  = threadIdx.x;
    const int m0   = blockIdx.y * 128, n0 = blockIdx.x * 128;
    const int lane = tid & 63, wid = tid >> 6;
    const int wm   = (wid >> 1) * 64, wn = (wid & 1) * 64;
    const int m16  = lane & 15, quad = lane >> 4;
    const int sw   = m16 & 7;
    const int isbf = *flag;

    const int srow = wid * 8 + (lane >> 3);
    const int sch  = lane & 7;

    f32x4 acc[4][4];
#pragma unroll
    for (int i = 0; i < 4; ++i)
#pragma unroll
        for (int j = 0; j < 4; ++j)
            acc[i][j] = (f32x4){0.f, 0.f, 0.f, 0.f};

    for (int k0 = 0; k0 < K; k0 += 64) {
#pragma unroll
        for (int g = 0; g < 4; ++g) {
            int r  = g * 32 + srow;
            int cg = sch ^ (r & 7);
            gl2lds16(&A[(size_t)(m0 + r) * K + k0 + cg * 8], &As[r * 64 + sch * 8]);
            gl2lds16(&Bt[(size_t)(n0 + r) * K + k0 + cg * 8], &Bs[r * 64 + sch * 8]);
        }
        __syncthreads();
#pragma unroll
        for (int ks = 0; ks < 2; ++ks) {
            bf16x8 a[4], b[4];
#pragma unroll
            for (int i = 0; i < 4; ++i) {
                int row = wm + i * 16 + m16;
                a[i] = *(bf16x8*)&As[row * 64 + (((ks * 4 + quad) ^ sw) * 8)];
            }
#pragma unroll
            for (int j = 0; j < 4; ++j) {
                int row = wn + j * 16 + m16;
                b[j] = *(bf16x8*)&Bs[row * 64 + (((ks * 4 + quad) ^ sw) * 8)];
            }
#pragma unroll
            for (int i = 0; i < 4; ++i)
#pragma unroll
                for (int j = 0; j < 4; ++j)
                    acc[i][j] = __builtin_amdgcn_mfma_f32_16x16x32_bf16(
                        a[i], b[j], acc[i][j], 0, 0, 0);
        }
        __syncthreads();
    }

    const bool out_f32 = final_out && !isbf;
#pragma unroll
    for (int i = 0; i < 4; ++i) {
        int grow = m0 + wm + i * 16 + quad * 4;
#pragma unroll
        for (int j = 0; j < 4; ++j) {
            int gcol = n0 + wn + j * 16 + m16;
            float bv = isbf ? bf2f(((const u16*)bias)[gcol])
                            : ((const float*)bias)[gcol];
#pragma unroll
            for (int r = 0; r < 4; ++r) {
                float val = acc[i][j][r] + bv;
                size_t idx = (size_t)(grow + r) * N + gcol;
                if (out_f32) ((float*)C)[idx] = val;
                else         ((u16*)C)[idx]   = f2bf(val);
            }
        }
    }
}

// ---------------------------------------------------------------------------
// Flash attention (causal), S^T orientation, exp2-domain (Q pre-scaled),
// NO online max. 128x128 tiles, 4-wave blocks, double-buffered K/V DMA,
// ONE barrier per tile-iter, Ps 128x64 half-buffer. LOAD-BALANCED pairing
// + XCD-PINNED remap (bh == lin mod 8 -> per-XCD K/V set = 4 MB = L2).
// LDS 80 KB -> 2 blocks/CU. Swizzled; Ps same-wave private.
// ---------------------------------------------------------------------------
__global__ __launch_bounds__(256, 2) void attn_flash(
    const u16* __restrict__ Q, const u16* __restrict__ Kb,
    const u16* __restrict__ Vt, u16* __restrict__ O, int T, int C)
{
    __shared__ __align__(16) u16 Ks[2][128 * 64];    // [s][d], swizzled
    __shared__ __align__(16) u16 Vts[2][64 * 128];   // [d][s], swizzled
    __shared__ __align__(16) u16 Ps[128 * 64];       // [q][s_half], swizzled

    const int tid  = threadIdx.x;
    const int lane = tid & 63, wid = tid >> 6;
    const int m16  = lane & 15, quad = lane >> 4;
    const int sw   = m16 & 7;                      // XOR swizzle key
    const float NEG = -3.0e4f;                     // exp2(NEG) == 0

    // XCD-pinning remap: lin = bx + 8*(y + 16*z), 0..511
    const int lin = (int)(blockIdx.x +
                          gridDim.x * (blockIdx.y + gridDim.y * blockIdx.z));
    const int bh  = (lin & 7) + 8 * ((lin >> 3) & 7);   // 0..63, == lin mod 8
    const int bx  = lin >> 6;                           // 0..7
    const int b = bh >> 4, h = bh & 15;

    const size_t headoff = ((size_t)b * T) * C + h * 64;
    const size_t vthead  = ((size_t)bh * 64) * T;
    const int ntiles = 16;                              // q-tiles of 128 rows

    for (int phase = 0; phase < 2; ++phase) {
        const int qt = phase ? bx : (ntiles - 1) - bx;
        if (phase) __syncthreads();   // protect LDS from phase-0 reads

        // Q B-fragments (pre-scaled by 1/8*log2e in gemm_qkv)
        bf16x8 aq[2][2];
#pragma unroll
        for (int i = 0; i < 2; ++i)
#pragma unroll
            for (int ks = 0; ks < 2; ++ks)
                aq[i][ks] = *(const bf16x8*)&Q[headoff +
                    (size_t)(qt * 128 + wid * 32 + i * 16 + m16) * C +
                    ks * 32 + quad * 8];

        // prologue: DMA tile 0 into buffer 0
#pragma unroll
        for (int g = 0; g < 4; ++g) {
            int r  = g * 32 + wid * 8 + (lane >> 3);
            int cg = (lane & 7) ^ (r & 7);
            gl2lds16(&Kb[headoff + (size_t)r * C + cg * 8],
                     &Ks[0][r * 64 + (lane & 7) * 8]);
        }
#pragma unroll
        for (int g = 0; g < 4; ++g) {
            int r  = g * 16 + wid * 4 + (lane >> 4);
            int cg = (lane & 15) ^ (r & 7);
            gl2lds16(&Vt[vthead + (size_t)r * T + cg * 8],
                     &Vts[0][r * 128 + (lane & 15) * 8]);
        }

        float l_run[2] = {0.f, 0.f};
        f32x4 o_acc[2][4];
#pragma unroll
        for (int i = 0; i < 2; ++i)
#pragma unroll
            for (int n = 0; n < 4; ++n)
                o_acc[i][n] = (f32x4){0.f, 0.f, 0.f, 0.f};

        for (int st = 0; st <= qt; ++st) {
            __syncthreads();   // tile st resident; prev-tile reads done
            const int cur = st & 1;

            // prefetch tile st+1 (drains at NEXT barrier)
            if (st < qt) {
                const int nxt = cur ^ 1;
#pragma unroll
                for (int g = 0; g < 4; ++g) {
                    int r  = g * 32 + wid * 8 + (lane >> 3);
                    int cg = (lane & 7) ^ (r & 7);
                    gl2lds16(&Kb[headoff + (size_t)((st + 1) * 128 + r) * C + cg * 8],
                             &Ks[nxt][r * 64 + (lane & 7) * 8]);
                }
#pragma unroll
                for (int g = 0; g < 4; ++g) {
                    int r  = g * 16 + wid * 4 + (lane >> 4);
                    int cg = (lane & 15) ^ (r & 7);
                    gl2lds16(&Vt[vthead + (size_t)r * T + (st + 1) * 128 + cg * 8],
                             &Vts[nxt][r * 128 + (lane & 15) * 8]);
                }
            }

            // S^T = K Q^T : lane's q = i*16+m16 (col), s = j*16+quad*4+r (row)
            f32x4 sacc[2][8];
#pragma unroll
            for (int i = 0; i < 2; ++i)
#pragma unroll
                for (int j = 0; j < 8; ++j)
                    sacc[i][j] = (f32x4){0.f, 0.f, 0.f, 0.f};
#pragma unroll
            for (int ks = 0; ks < 2; ++ks) {
                bf16x8 bk[8];
#pragma unroll
                for (int j = 0; j < 8; ++j)
                    bk[j] = *(bf16x8*)&Ks[cur][(j * 16 + m16) * 64 +
                                              (((ks * 4 + quad) ^ sw) * 8)];
#pragma unroll
                for (int i = 0; i < 2; ++i)
#pragma unroll
                    for (int j = 0; j < 8; ++j)
                        sacc[i][j] = __builtin_amdgcn_mfma_f32_16x16x32_bf16(
                            bk[j], aq[i][ks], sacc[i][j], 0, 0, 0);
            }

            // diagonal tile: causal mask (wave-uniform branch)
            if (st == qt) {
#pragma unroll
                for (int i = 0; i < 2; ++i) {
                    const int q_in = wid * 32 + i * 16 + m16;
#pragma unroll
                    for (int j = 0; j < 8; ++j)
#pragma unroll
                        for (int r = 0; r < 4; ++r)
                            if ((j * 16 + quad * 4 + r) > q_in)
                                sacc[i][j][r] = NEG;
                }
            }

            // exp2 (pre-scaled: no mul, no max) + Ps write + PV per s-half
            float rs[2] = {0.f, 0.f};
#pragma unroll
            for (int half = 0; half < 2; ++half) {
#pragma unroll
                for (int i = 0; i < 2; ++i) {
#pragma unroll
                    for (int jh = 0; jh < 4; ++jh) {
                        int j = half * 4 + jh;
                        float p0 = exp2f(sacc[i][j][0]);
                        float p1 = exp2f(sacc[i][j][1]);
                        float p2 = exp2f(sacc[i][j][2]);
                        float p3 = exp2f(sacc[i][j][3]);
                        rs[i] += (p0 + p1) + (p2 + p3);
                        unsigned lo = ((__float_as_uint(p0) + 0x8000u) >> 16) |
                                      ((__float_as_uint(p1) + 0x8000u) & 0xFFFF0000u);
                        unsigned hi = ((__float_as_uint(p2) + 0x8000u) >> 16) |
                                      ((__float_as_uint(p3) + 0x8000u) & 0xFFFF0000u);
                        *(uint2*)&Ps[(wid * 32 + i * 16 + m16) * 64 +
                                     (((jh * 2 + (quad >> 1)) ^ sw) * 8) +
                                     (quad & 1) * 4] = make_uint2(lo, hi);
                    }
                }
                // PV for this half (Ps same-wave private: no barrier)
#pragma unroll
                for (int k4l = 0; k4l < 2; ++k4l) {
                    int k4 = half * 2 + k4l;
                    bf16x8 ap[2], bv[4];
#pragma unroll
                    for (int i = 0; i < 2; ++i)
                        ap[i] = *(bf16x8*)&Ps[(wid * 32 + i * 16 + m16) * 64 +
                                              (((k4l * 4 + quad) ^ sw) * 8)];
#pragma unroll
                    for (int n = 0; n < 4; ++n)
                        bv[n] = *(bf16x8*)&Vts[cur][(n * 16 + m16) * 128 +
                                                   (((k4 * 4 + quad) ^ sw) * 8)];
#pragma unroll
                    for (int i = 0; i < 2; ++i)
#pragma unroll
                        for (int n = 0; n < 4; ++n)
                            o_acc[i][n] = __builtin_amdgcn_mfma_f32_16x16x32_bf16(
                                ap[i], bv[n], o_acc[i][n], 0, 0, 0);
                }
            }
            l_run[0] += rs[0];
            l_run[1] += rs[1];
        }

        // epilogue: quad-reduce l, normalize, store
#pragma unroll
        for (int i = 0; i < 2; ++i) {
            l_run[i] += __shfl_xor(l_run[i], 16);
            l_run[i] += __shfl_xor(l_run[i], 32);
            float linv[4];
#pragma unroll
            for (int r = 0; r < 4; ++r)
                linv[r] = 1.f / __shfl(l_run[i], quad * 4 + r);
#pragma unroll
            for (int n = 0; n < 4; ++n) {
#pragma unroll
                for (int r = 0; r < 4; ++r) {
                    int tq = qt * 128 + wid * 32 + i * 16 + quad * 4 + r;
                    O[((size_t)b * T + tq) * C + h * 64 + n * 16 + m16] =
                        f2bf(o_acc[i][n][r] * linv[r]);
                }
            }
        }
    }
}

// ---------------------------------------------------------------------------
extern "C" void kernel_launch(void* const* d_in, const int* in_sizes, int n_in,
                              void* d_out, int out_size, void* d_ws, size_t ws_size,
                              hipStream_t stream)
{
    const void* x  = d_in[0];
    const void* Wq = d_in[1];
    const void* bq = d_in[2];
    const void* Wk = d_in[3];
    const void* bk = d_in[4];
    const void* Wv = d_in[5];
    const void* bv = d_in[6];
    const void* Wp = d_in[7];
    const void* bp = d_in[8];

    const int Bb = 4, T = 2048, C = 1024, H = 16;
    const int M = Bb * T, N = C, K = C;

    u16* wsp = (u16*)d_ws;
    const size_t WSZ = (size_t)C * C;
    const size_t MSZ = (size_t)M * C;
    u16* WtQKV = wsp;                 // [3072][1024]
    u16* WtP   = wsp + 3 * WSZ;
    u16* xb    = wsp + 4 * WSZ;
    u16* Qb    = xb + MSZ;            // Q pre-scaled by 1/8*log2(e)
    u16* Kbf   = Qb + MSZ;
    u16* Vtb   = Kbf + MSZ;           // V^T: [(b*16+h)*64+d][T]
    u16* tmp   = Vtb + MSZ;           // attention out
    int* flag  = (int*)(tmp + MSZ);

    detect_dtype<<<1, 128, 0, stream>>>((const u16*)x, flag);
    convert_in<<<(int)(MSZ / 4 / 256), 256, 0, stream>>>(x, xb, MSZ / 4, flag);

    dim3 tg(C / 32, C / 32, 4), tb(256);
    transpose_all<<<tg, tb, 0, stream>>>(Wq, Wk, Wv, Wp, WtQKV, WtP, C, flag);

    dim3 qg(3 * N / 128, M / 128), qb(256);
    gemm_qkv<<<qg, qb, 0, stream>>>(xb, WtQKV, bq, bk, bv, Qb, Kbf, Vtb,
                                    M, K, flag);

    dim3 ag(T / 256, H, Bb), ab(256);   // 512 blocks, XCD-pinned remap inside
    attn_flash<<<ag, ab, 0, stream>>>(Qb, Kbf, Vtb, tmp, T, C);

    dim3 gg(N / 128, M / 128), gb(256);
    gemm_bias<<<gg, gb, 0, stream>>>(tmp, WtP, bp, d_out, M, N, K, 1, flag);
}